// Round 1
// 705.098 us; speedup vs baseline: 1.1934x; 1.1934x over previous
//
#include <hip/hip_runtime.h>

#define D    768
#define T    16384
#define TQ   8192
#define BINS 1024
#define K1   1536            // conv GEMM K = D*2
#define LKS  40              // LDS k-stride (f16): 32 + 8 pad -> 80 B = 5x16B (odd) -> ~2-way
#define PK   72              // pack LDS k-stride (f16): 64 + 8 -> 144 B = 9x16B (odd)

typedef _Float16 f16;
typedef _Float16 h8 __attribute__((ext_vector_type(8)));
typedef _Float16 h4 __attribute__((ext_vector_type(4)));
typedef float    f32x4 __attribute__((ext_vector_type(4)));

// ---------------------------------------------------------------------------
// cnorm[k] = ||codebook[k]||^2  (fp32, exact-order irrelevant)
// ---------------------------------------------------------------------------
__global__ __launch_bounds__(64) void cnorm_kernel(const float* __restrict__ cb,
                                                   float* __restrict__ cnorm) {
    int bin  = blockIdx.x;
    int lane = threadIdx.x;
    const float* row = cb + bin * D;
    float s = 0.f;
    for (int k = lane; k < D; k += 64) { float v = row[k]; s += v * v; }
    #pragma unroll
    for (int off = 32; off > 0; off >>= 1) s += __shfl_down(s, off);
    if (lane == 0) cnorm[bin] = s;
}

// ---------------------------------------------------------------------------
// Elementwise fp32 -> (hi, lo) fp16 split planes.  v = hi + lo/2048 + O(2^-22)
// ---------------------------------------------------------------------------
__global__ __launch_bounds__(256) void split_kernel(const float* __restrict__ src,
                                                    f16* __restrict__ hi,
                                                    f16* __restrict__ lo, int n4) {
    int i = blockIdx.x * 256 + threadIdx.x;
    if (i >= n4) return;
    float4 v = ((const float4*)src)[i];
    f16 h0 = (f16)v.x, h1 = (f16)v.y, h2 = (f16)v.z, h3 = (f16)v.w;
    h4 vh = {h0, h1, h2, h3};
    h4 vl = {(f16)((v.x - (float)h0) * 2048.f), (f16)((v.y - (float)h1) * 2048.f),
             (f16)((v.z - (float)h2) * 2048.f), (f16)((v.w - (float)h3) * 2048.f)};
    ((h4*)hi)[i] = vh;
    ((h4*)lo)[i] = vl;
}

// ---------------------------------------------------------------------------
// Pack ssl batch-0 [D][T] -> A[t'][k] fp16 hi/lo planes, k = 2*i + s
// (i = input channel, s = conv tap).  LDS-tiled transpose: 128 t' x 64 k.
// ---------------------------------------------------------------------------
__global__ __launch_bounds__(256) void pack_a_kernel(const float* __restrict__ ssl,
                                                     f16* __restrict__ Ahi,
                                                     f16* __restrict__ Alo) {
    __shared__ __align__(16) f16 lhi[128 * PK];
    __shared__ __align__(16) f16 llo[128 * PK];
    int tid = threadIdx.x;
    int tb = blockIdx.x * 128;          // t' base (64 tiles)
    int kb = blockIdx.y * 64;           // k base (24 tiles)
    int ib = kb >> 1;                   // input-channel base
    #pragma unroll
    for (int it = 0; it < 8; ++it) {
        int idx = tid + 256 * it;       // 0..2047 over 32 rows x 64 float4
        int ii = idx >> 6;              // channel 0..31
        int c4 = idx & 63;              // float4 col -> 2 t' values
        float4 v = *(const float4*)&ssl[(ib + ii) * T + 2 * tb + 4 * c4];
        int t0 = 2 * c4, k0 = 2 * ii;
        f16 h;
        h = (f16)v.x; lhi[t0*PK + k0]       = h; llo[t0*PK + k0]       = (f16)((v.x - (float)h) * 2048.f);
        h = (f16)v.y; lhi[t0*PK + k0 + 1]   = h; llo[t0*PK + k0 + 1]   = (f16)((v.y - (float)h) * 2048.f);
        h = (f16)v.z; lhi[(t0+1)*PK + k0]   = h; llo[(t0+1)*PK + k0]   = (f16)((v.z - (float)h) * 2048.f);
        h = (f16)v.w; lhi[(t0+1)*PK + k0+1] = h; llo[(t0+1)*PK + k0+1] = (f16)((v.w - (float)h) * 2048.f);
    }
    __syncthreads();
    #pragma unroll
    for (int it = 0; it < 4; ++it) {    // 128 rows x 8 chunks of 8 f16, per plane
        int w = tid + 256 * it;
        int tl = w >> 3, g = w & 7;
        h8 vh = *(const h8*)&lhi[tl * PK + 8 * g];
        h8 vl = *(const h8*)&llo[tl * PK + 8 * g];
        int off = (tb + tl) * K1 + kb + 8 * g;
        *(h8*)&Ahi[off] = vh;
        *(h8*)&Alo[off] = vl;
    }
}

// ---------------------------------------------------------------------------
// Conv as split-fp16 MFMA GEMM: X[t'][o] = sum_k A[t'][k] * W[o][k] + bias[o].
// Block 128(M=t') x 128(N=o), BK=32, 4 waves of 64x64 (4x4 16x16x32 frags).
// 3 MFMA passes: hi*hi into acc; (hi*lo + lo*hi) into temp, folded * 2^-11.
// Epilogue writes X directly as fp16 hi/lo planes for the score GEMM.
// ---------------------------------------------------------------------------
__global__ __launch_bounds__(256) void conv_mfma_kernel(
    const f16* __restrict__ Ahi, const f16* __restrict__ Alo,   // [TQ][K1]
    const f16* __restrict__ Whi, const f16* __restrict__ Wlo,   // [D][K1]
    const float* __restrict__ bias,
    f16* __restrict__ Xhi, f16* __restrict__ Xlo)               // [TQ][D]
{
    __shared__ __align__(16) f16 sAh[128 * LKS], sAl[128 * LKS];
    __shared__ __align__(16) f16 sBh[128 * LKS], sBl[128 * LKS];
    int tid = threadIdx.x;
    int lane = tid & 63, wid = tid >> 6;
    int wm = wid >> 1, wn = wid & 1;
    int l15 = lane & 15, lk = lane >> 4;
    int mb = blockIdx.y * 128;
    int nb = blockIdx.x * 128;
    const f32x4 zero4 = {0.f, 0.f, 0.f, 0.f};
    f32x4 acc[4][4];
    #pragma unroll
    for (int i = 0; i < 4; ++i)
        #pragma unroll
        for (int j = 0; j < 4; ++j) acc[i][j] = zero4;

    int sr = tid >> 2, sg = (tid & 3) * 8;
    for (int k0 = 0; k0 < K1; k0 += 32) {
        __syncthreads();
        #pragma unroll
        for (int rep = 0; rep < 2; ++rep) {
            int r = sr + rep * 64;
            int ga = (mb + r) * K1 + k0 + sg;
            int gb = (nb + r) * K1 + k0 + sg;
            int ls = r * LKS + sg;
            *(h8*)&sAh[ls] = *(const h8*)&Ahi[ga];
            *(h8*)&sAl[ls] = *(const h8*)&Alo[ga];
            *(h8*)&sBh[ls] = *(const h8*)&Whi[gb];
            *(h8*)&sBl[ls] = *(const h8*)&Wlo[gb];
        }
        __syncthreads();
        h8 ah[4], al[4];
        #pragma unroll
        for (int mf = 0; mf < 4; ++mf) {
            int ro = (wm * 64 + mf * 16 + l15) * LKS + 8 * lk;
            ah[mf] = *(const h8*)&sAh[ro];
            al[mf] = *(const h8*)&sAl[ro];
        }
        #pragma unroll
        for (int nf = 0; nf < 4; ++nf) {
            int co = (wn * 64 + nf * 16 + l15) * LKS + 8 * lk;
            h8 bh = *(const h8*)&sBh[co];
            h8 bl = *(const h8*)&sBl[co];
            #pragma unroll
            for (int mf = 0; mf < 4; ++mf) {
                acc[mf][nf] = __builtin_amdgcn_mfma_f32_16x16x32_f16(ah[mf], bh, acc[mf][nf], 0, 0, 0);
                f32x4 t = __builtin_amdgcn_mfma_f32_16x16x32_f16(ah[mf], bl, zero4, 0, 0, 0);
                t = __builtin_amdgcn_mfma_f32_16x16x32_f16(al[mf], bh, t, 0, 0, 0);
                acc[mf][nf] += t * 4.8828125e-4f;   // fold cross terms / 2048
            }
        }
    }
    #pragma unroll
    for (int nf = 0; nf < 4; ++nf) {
        int col = nb + wn * 64 + nf * 16 + l15;
        float bv = bias[col];
        #pragma unroll
        for (int mf = 0; mf < 4; ++mf) {
            int row = mb + wm * 64 + mf * 16 + lk * 4;
            #pragma unroll
            for (int r = 0; r < 4; ++r) {
                float x = acc[mf][nf][r] + bv;
                f16 h = (f16)x;
                int o = (row + r) * D + col;
                Xhi[o] = h;
                Xlo[o] = (f16)((x - (float)h) * 2048.f);
            }
        }
    }
}

// ---------------------------------------------------------------------------
// Score: dot[row][bin] via split-fp16 MFMA, fused s = cnorm - 2*dot and
// per-row partial argmin over this block's 128 bins (2 slices of 64/wave-col).
// C/D frag mapping: col = lane&15, row = (lane>>4)*4 + reg.
// ---------------------------------------------------------------------------
__global__ __launch_bounds__(256) void score_mfma_kernel(
    const f16* __restrict__ Xhi, const f16* __restrict__ Xlo,   // [TQ][D]
    const f16* __restrict__ CBhi, const f16* __restrict__ CBlo, // [BINS][D]
    const float* __restrict__ cnorm,
    float* __restrict__ pval, int* __restrict__ pidx)           // [TQ][16]
{
    __shared__ __align__(16) f16 sAh[128 * LKS], sAl[128 * LKS];
    __shared__ __align__(16) f16 sBh[128 * LKS], sBl[128 * LKS];
    int tid = threadIdx.x;
    int lane = tid & 63, wid = tid >> 6;
    int wm = wid >> 1, wn = wid & 1;
    int l15 = lane & 15, lk = lane >> 4;
    int mb = blockIdx.y * 128;
    int nb = blockIdx.x * 128;
    const f32x4 zero4 = {0.f, 0.f, 0.f, 0.f};
    f32x4 acc[4][4];
    #pragma unroll
    for (int i = 0; i < 4; ++i)
        #pragma unroll
        for (int j = 0; j < 4; ++j) acc[i][j] = zero4;

    int sr = tid >> 2, sg = (tid & 3) * 8;
    for (int k0 = 0; k0 < D; k0 += 32) {
        __syncthreads();
        #pragma unroll
        for (int rep = 0; rep < 2; ++rep) {
            int r = sr + rep * 64;
            int ga = (mb + r) * D + k0 + sg;
            int gb = (nb + r) * D + k0 + sg;
            int ls = r * LKS + sg;
            *(h8*)&sAh[ls] = *(const h8*)&Xhi[ga];
            *(h8*)&sAl[ls] = *(const h8*)&Xlo[ga];
            *(h8*)&sBh[ls] = *(const h8*)&CBhi[gb];
            *(h8*)&sBl[ls] = *(const h8*)&CBlo[gb];
        }
        __syncthreads();
        h8 ah[4], al[4];
        #pragma unroll
        for (int mf = 0; mf < 4; ++mf) {
            int ro = (wm * 64 + mf * 16 + l15) * LKS + 8 * lk;
            ah[mf] = *(const h8*)&sAh[ro];
            al[mf] = *(const h8*)&sAl[ro];
        }
        #pragma unroll
        for (int nf = 0; nf < 4; ++nf) {
            int co = (wn * 64 + nf * 16 + l15) * LKS + 8 * lk;
            h8 bh = *(const h8*)&sBh[co];
            h8 bl = *(const h8*)&sBl[co];
            #pragma unroll
            for (int mf = 0; mf < 4; ++mf) {
                acc[mf][nf] = __builtin_amdgcn_mfma_f32_16x16x32_f16(ah[mf], bh, acc[mf][nf], 0, 0, 0);
                f32x4 t = __builtin_amdgcn_mfma_f32_16x16x32_f16(ah[mf], bl, zero4, 0, 0, 0);
                t = __builtin_amdgcn_mfma_f32_16x16x32_f16(al[mf], bh, t, 0, 0, 0);
                acc[mf][nf] += t * 4.8828125e-4f;
            }
        }
    }
    // epilogue: s = cnorm[col] - 2*dot; per-row argmin over this wave's 64 cols
    float cn[4];
    #pragma unroll
    for (int nf = 0; nf < 4; ++nf) cn[nf] = cnorm[nb + wn * 64 + nf * 16 + l15];
    int slice = blockIdx.x * 2 + wn;         // 16 slices of 64 ascending bins
    #pragma unroll
    for (int mf = 0; mf < 4; ++mf) {
        #pragma unroll
        for (int r = 0; r < 4; ++r) {
            float v = 3.4e38f; int ix = 0;
            #pragma unroll
            for (int nf = 0; nf < 4; ++nf) {   // cols ascend with nf: ties -> lowest
                float s = cn[nf] - 2.f * acc[mf][nf][r];
                int col = nb + wn * 64 + nf * 16 + l15;
                if (s < v) { v = s; ix = col; }
            }
            #pragma unroll
            for (int off = 8; off > 0; off >>= 1) {  // reduce 16-lane col group
                float ov = __shfl_xor(v, off);
                int   oi = __shfl_xor(ix, off);
                if (ov < v || (ov == v && oi < ix)) { v = ov; ix = oi; }
            }
            if (l15 == 0) {
                int row = mb + wm * 64 + mf * 16 + lk * 4 + r;
                pval[row * 16 + slice] = v;
                pidx[row * 16 + slice] = ix;
            }
        }
    }
}

// ---------------------------------------------------------------------------
// Final reduce over 16 ascending bin-slices (strict < keeps lowest index).
// ---------------------------------------------------------------------------
__global__ __launch_bounds__(256) void argmin_final_kernel(
    const float* __restrict__ pval, const int* __restrict__ pidx,
    int* __restrict__ out)
{
    int r = blockIdx.x * 256 + threadIdx.x;
    float best = 3.4e38f; int bi = 0;
    #pragma unroll
    for (int s = 0; s < 16; ++s) {
        float v = pval[r * 16 + s];
        if (v < best) { best = v; bi = pidx[r * 16 + s]; }
    }
    out[r] = bi;
}

extern "C" void kernel_launch(void* const* d_in, const int* in_sizes, int n_in,
                              void* d_out, int out_size, void* d_ws, size_t ws_size,
                              hipStream_t stream) {
    const float* ssl = (const float*)d_in[0];  // [8, 768, 16384]
    const float* W   = (const float*)d_in[1];  // [768, 768, 2] == [768][1536] k=2i+s
    const float* bia = (const float*)d_in[2];  // [768]
    const float* cb  = (const float*)d_in[3];  // [1024, 768]
    int* out = (int*)d_out;                    // [8192] int32 codes

    char* p = (char*)d_ws;
    float* cnorm = (float*)p;  p += 1024 * 4;
    f16* Whi  = (f16*)p;  p += (size_t)D * K1 * 2;
    f16* Wlo  = (f16*)p;  p += (size_t)D * K1 * 2;
    f16* CBhi = (f16*)p;  p += (size_t)BINS * D * 2;
    f16* CBlo = (f16*)p;  p += (size_t)BINS * D * 2;
    f16* Ahi  = (f16*)p;  p += (size_t)TQ * K1 * 2;
    f16* Alo  = (f16*)p;  p += (size_t)TQ * K1 * 2;
    f16* Xhi  = (f16*)p;  p += (size_t)TQ * D * 2;
    f16* Xlo  = (f16*)p;  p += (size_t)TQ * D * 2;
    float* pval = (float*)p;  p += (size_t)TQ * 16 * 4;
    int*   pidx = (int*)p;    p += (size_t)TQ * 16 * 4;
    // total ~84.5 MB (<< the ~1.6 GB workspace evidenced by the poison fill)

    cnorm_kernel<<<BINS, 64, 0, stream>>>(cb, cnorm);
    split_kernel<<<(D * K1 / 4) / 256, 256, 0, stream>>>(W, Whi, Wlo, D * K1 / 4);
    split_kernel<<<(BINS * D / 4) / 256, 256, 0, stream>>>(cb, CBhi, CBlo, BINS * D / 4);
    pack_a_kernel<<<dim3(TQ / 128, K1 / 64), 256, 0, stream>>>(ssl, Ahi, Alo);
    conv_mfma_kernel<<<dim3(D / 128, TQ / 128), 256, 0, stream>>>(Ahi, Alo, Whi, Wlo, bia, Xhi, Xlo);
    score_mfma_kernel<<<dim3(BINS / 128, TQ / 128), 256, 0, stream>>>(Xhi, Xlo, CBhi, CBlo, cnorm, pval, pidx);
    argmin_final_kernel<<<TQ / 256, 256, 0, stream>>>(pval, pidx, out);
}

// Round 2
// 587.674 us; speedup vs baseline: 1.4319x; 1.1998x over previous
//
#include <hip/hip_runtime.h>

#define D    768
#define T    16384
#define TQ   8192
#define BINS 1024
#define K1   1536            // conv GEMM K = D*2
#define NKA  (K1 / 32)       // 48 k-blocks (conv operands)
#define NKS  (D / 32)        // 24 k-blocks (score operands)
#define FRAG 1024            // bytes per fragment: 64 lanes x 16 B

typedef _Float16 f16;
typedef _Float16 h8 __attribute__((ext_vector_type(8)));
typedef float    f32x4 __attribute__((ext_vector_type(4)));

// Fragment-major layout, all f16 planes:
//   plane[(r16 * NK + kblk) * 64 + lane] is an h8 (16 B);
//   lane l holds row r16*16 + (l&15), k = kblk*32 + 8*(l>>4) + 0..7
// This matches exactly the mfma_f32_16x16x32_f16 A/B operand read pattern
// (verified by round-1 passing with the same per-lane h8 semantics).

__device__ __forceinline__ void gl_lds16(const void* g, void* l) {
    __builtin_amdgcn_global_load_lds(
        (const __attribute__((address_space(1))) void*)g,
        (__attribute__((address_space(3))) void*)l, 16, 0, 0);
}

// ---------------------------------------------------------------------------
// cnorm[k] = ||codebook[k]||^2
// ---------------------------------------------------------------------------
__global__ __launch_bounds__(64) void cnorm_kernel(const float* __restrict__ cb,
                                                   float* __restrict__ cnorm) {
    int bin  = blockIdx.x;
    int lane = threadIdx.x;
    const float* row = cb + bin * D;
    float s = 0.f;
    for (int k = lane; k < D; k += 64) { float v = row[k]; s += v * v; }
    #pragma unroll
    for (int off = 32; off > 0; off >>= 1) s += __shfl_down(s, off);
    if (lane == 0) cnorm[bin] = s;
}

// ---------------------------------------------------------------------------
// Row-major fp32 [R][K] -> fragment-major fp16 hi/lo planes. One frag/wave.
// ---------------------------------------------------------------------------
__global__ __launch_bounds__(256) void pack_b_kernel(
    const float* __restrict__ src, f16* __restrict__ hi, f16* __restrict__ lo,
    int K, int nfrag) {
    int wid = threadIdx.x >> 6, lane = threadIdx.x & 63;
    int fid = blockIdx.x * 4 + wid;
    if (fid >= nfrag) return;
    int nk = K >> 5;
    int r16 = fid / nk, kblk = fid - r16 * nk;
    int row = r16 * 16 + (lane & 15);
    int k0  = kblk * 32 + 8 * (lane >> 4);
    const float* s = src + (size_t)row * K + k0;
    float4 v0 = *(const float4*)s;
    float4 v1 = *(const float4*)(s + 4);
    float vv[8] = {v0.x, v0.y, v0.z, v0.w, v1.x, v1.y, v1.z, v1.w};
    h8 vh, vl;
    #pragma unroll
    for (int j = 0; j < 8; ++j) {
        f16 h = (f16)vv[j];
        vh[j] = h;
        vl[j] = (f16)((vv[j] - (float)h) * 2048.f);
    }
    size_t off = ((size_t)fid * 64 + lane) * 8;
    *(h8*)&hi[off] = vh;
    *(h8*)&lo[off] = vl;
}

// ---------------------------------------------------------------------------
// ssl batch-0 [D][T] -> A fragment-major hi/lo, k = 2*i + s (conv k=2,s=2).
// No LDS needed: each lane gathers its own 8 k-elements (4 float2 loads).
// ---------------------------------------------------------------------------
__global__ __launch_bounds__(256) void pack_a_kernel(const float* __restrict__ ssl,
                                                     f16* __restrict__ hi,
                                                     f16* __restrict__ lo) {
    int wid = threadIdx.x >> 6, lane = threadIdx.x & 63;
    int kblk = blockIdx.x;                 // 0..47
    int l15 = lane & 15, lk = lane >> 4;
    #pragma unroll
    for (int q = 0; q < 2; ++q) {
        int tblk = blockIdx.y * 8 + wid * 2 + q;   // t'-group
        int tp = tblk * 16 + l15;
        int i0 = kblk * 16 + 4 * lk;               // input channel base
        float vv[8];
        #pragma unroll
        for (int ii = 0; ii < 4; ++ii) {           // k = 8*lk + 2*ii + s
            float2 v = *(const float2*)&ssl[(size_t)(i0 + ii) * T + 2 * tp];
            vv[2 * ii]     = v.x;
            vv[2 * ii + 1] = v.y;
        }
        h8 vh, vl;
        #pragma unroll
        for (int j = 0; j < 8; ++j) {
            f16 h = (f16)vv[j];
            vh[j] = h;
            vl[j] = (f16)((vv[j] - (float)h) * 2048.f);
        }
        size_t off = ((size_t)(tblk * NKA + kblk) * 64 + lane) * 8;
        *(h8*)&hi[off] = vh;
        *(h8*)&lo[off] = vl;
    }
}

// ---------------------------------------------------------------------------
// Conv as split-fp16 MFMA GEMM, m97-style: global_load_lds(16B) staging into
// linear fragment-major LDS (32 KB: Ah|Al|Bh|Bl, 8 frags each).  Block
// 128x128, BK=32, 4 waves of 64x64 (4x4 frags), 3 MFMA passes per frag.
// Epilogue: 4-slab LDS transpose -> X written fragment-major for score.
// ---------------------------------------------------------------------------
__global__ __launch_bounds__(256, 2) void conv_mfma_kernel(
    const f16* __restrict__ Ah, const f16* __restrict__ Al,   // [TQ/16][NKA] frags
    const f16* __restrict__ Bh, const f16* __restrict__ Bl,   // [D/16][NKA] frags
    const float* __restrict__ bias,
    f16* __restrict__ Xhi, f16* __restrict__ Xlo)             // [TQ/16][NKS] frags
{
    __shared__ __align__(16) char smem[32768];
    int tid = threadIdx.x, lane = tid & 63, wid = tid >> 6;
    int wm = wid >> 1, wn = wid & 1;
    int l15 = lane & 15, lk = lane >> 4;
    int mb = blockIdx.y * 128, nb = blockIdx.x * 128;
    int mb16 = mb >> 4, nb16 = nb >> 4;

    // each wave stages one plane (8 frags = 8 KB) per K-step
    const f16* gsrc; int blk16;
    if      (wid == 0) { gsrc = Ah; blk16 = mb16; }
    else if (wid == 1) { gsrc = Al; blk16 = mb16; }
    else if (wid == 2) { gsrc = Bh; blk16 = nb16; }
    else               { gsrc = Bl; blk16 = nb16; }
    const char* gw = (const char*)gsrc + (size_t)blk16 * NKA * FRAG + lane * 16;
    char* lw = smem + wid * 8192;

    const f32x4 zero4 = {0.f, 0.f, 0.f, 0.f};
    f32x4 acc[4][4];
    #pragma unroll
    for (int i = 0; i < 4; ++i)
        #pragma unroll
        for (int j = 0; j < 4; ++j) acc[i][j] = zero4;

    for (int kblk = 0; kblk < NKA; ++kblk) {
        __syncthreads();
        #pragma unroll
        for (int f = 0; f < 8; ++f)
            gl_lds16(gw + (size_t)(f * NKA + kblk) * FRAG, lw + f * FRAG);
        __syncthreads();
        h8 ah[4], al[4];
        #pragma unroll
        for (int mf = 0; mf < 4; ++mf) {
            int fo = (wm * 4 + mf) * FRAG + lane * 16;
            ah[mf] = *(const h8*)(smem + fo);
            al[mf] = *(const h8*)(smem + 8192 + fo);
        }
        #pragma unroll
        for (int nf = 0; nf < 4; ++nf) {
            int fo = (wn * 4 + nf) * FRAG + lane * 16;
            h8 bh = *(const h8*)(smem + 16384 + fo);
            h8 bl = *(const h8*)(smem + 24576 + fo);
            #pragma unroll
            for (int mf = 0; mf < 4; ++mf) {
                acc[mf][nf] = __builtin_amdgcn_mfma_f32_16x16x32_f16(ah[mf], bh, acc[mf][nf], 0, 0, 0);
                f32x4 t = __builtin_amdgcn_mfma_f32_16x16x32_f16(ah[mf], bl, zero4, 0, 0, 0);
                t = __builtin_amdgcn_mfma_f32_16x16x32_f16(al[mf], bh, t, 0, 0, 0);
                acc[mf][nf] += t * 4.8828125e-4f;   // fold cross terms / 2048
            }
        }
    }

    // epilogue: acc lane layout is (col=l15, rows=lk*4+r) -> transpose through
    // LDS to score-fragment layout (t' per l&15, d-chunk per l>>4), in 4 slabs
    // of 32 rows (32x132 f32 = 16.9 KB, reuses smem).
    float* sb = (float*)smem;
    float bv[4];
    #pragma unroll
    for (int nf = 0; nf < 4; ++nf) bv[nf] = bias[nb + wn * 64 + nf * 16 + l15];
    #pragma unroll
    for (int s = 0; s < 4; ++s) {
        __syncthreads();
        if (wm == (s >> 1)) {
            #pragma unroll
            for (int mh = 0; mh < 2; ++mh) {
                int mf = (s & 1) * 2 + mh;
                int srow = mh * 16 + lk * 4;
                #pragma unroll
                for (int nf = 0; nf < 4; ++nf) {
                    int scol = wn * 64 + nf * 16 + l15;
                    #pragma unroll
                    for (int r = 0; r < 4; ++r)
                        sb[(srow + r) * 132 + scol] = acc[mf][nf][r] + bv[nf];
                }
            }
        }
        __syncthreads();
        #pragma unroll
        for (int h = 0; h < 2; ++h) {
            int f = wid * 2 + h;          // 0..7: tl = f&1, dbl = f>>1
            int tl = f & 1, dbl = f >> 1;
            int srow = tl * 16 + l15;
            int sd   = dbl * 32 + 8 * lk;
            float vv[8];
            #pragma unroll
            for (int j = 0; j < 8; ++j) vv[j] = sb[srow * 132 + sd + j];
            h8 vh, vl;
            #pragma unroll
            for (int j = 0; j < 8; ++j) {
                f16 hh = (f16)vv[j];
                vh[j] = hh;
                vl[j] = (f16)((vv[j] - (float)hh) * 2048.f);
            }
            int tblk_g = mb16 + s * 2 + tl;
            int dblk_g = (nb >> 5) + dbl;
            size_t off = ((size_t)(tblk_g * NKS + dblk_g) * 64 + lane) * 8;
            *(h8*)&Xhi[off] = vh;
            *(h8*)&Xlo[off] = vl;
        }
    }
}

// ---------------------------------------------------------------------------
// Score: dot via split-fp16 MFMA (same staging structure, K=768), fused
// s = cnorm - 2*dot + per-row partial argmin (16 slices of 64 bins).
// ---------------------------------------------------------------------------
__global__ __launch_bounds__(256, 2) void score_mfma_kernel(
    const f16* __restrict__ Ah, const f16* __restrict__ Al,   // X frags [TQ/16][NKS]
    const f16* __restrict__ Bh, const f16* __restrict__ Bl,   // CB frags [BINS/16][NKS]
    const float* __restrict__ cnorm,
    float* __restrict__ pval, int* __restrict__ pidx)         // [TQ][16]
{
    __shared__ __align__(16) char smem[32768];
    int tid = threadIdx.x, lane = tid & 63, wid = tid >> 6;
    int wm = wid >> 1, wn = wid & 1;
    int l15 = lane & 15, lk = lane >> 4;
    int mb = blockIdx.y * 128, nb = blockIdx.x * 128;
    int mb16 = mb >> 4, nb16 = nb >> 4;

    const f16* gsrc; int blk16;
    if      (wid == 0) { gsrc = Ah; blk16 = mb16; }
    else if (wid == 1) { gsrc = Al; blk16 = mb16; }
    else if (wid == 2) { gsrc = Bh; blk16 = nb16; }
    else               { gsrc = Bl; blk16 = nb16; }
    const char* gw = (const char*)gsrc + (size_t)blk16 * NKS * FRAG + lane * 16;
    char* lw = smem + wid * 8192;

    const f32x4 zero4 = {0.f, 0.f, 0.f, 0.f};
    f32x4 acc[4][4];
    #pragma unroll
    for (int i = 0; i < 4; ++i)
        #pragma unroll
        for (int j = 0; j < 4; ++j) acc[i][j] = zero4;

    for (int kblk = 0; kblk < NKS; ++kblk) {
        __syncthreads();
        #pragma unroll
        for (int f = 0; f < 8; ++f)
            gl_lds16(gw + (size_t)(f * NKS + kblk) * FRAG, lw + f * FRAG);
        __syncthreads();
        h8 ah[4], al[4];
        #pragma unroll
        for (int mf = 0; mf < 4; ++mf) {
            int fo = (wm * 4 + mf) * FRAG + lane * 16;
            ah[mf] = *(const h8*)(smem + fo);
            al[mf] = *(const h8*)(smem + 8192 + fo);
        }
        #pragma unroll
        for (int nf = 0; nf < 4; ++nf) {
            int fo = (wn * 4 + nf) * FRAG + lane * 16;
            h8 bh = *(const h8*)(smem + 16384 + fo);
            h8 bl = *(const h8*)(smem + 24576 + fo);
            #pragma unroll
            for (int mf = 0; mf < 4; ++mf) {
                acc[mf][nf] = __builtin_amdgcn_mfma_f32_16x16x32_f16(ah[mf], bh, acc[mf][nf], 0, 0, 0);
                f32x4 t = __builtin_amdgcn_mfma_f32_16x16x32_f16(ah[mf], bl, zero4, 0, 0, 0);
                t = __builtin_amdgcn_mfma_f32_16x16x32_f16(al[mf], bh, t, 0, 0, 0);
                acc[mf][nf] += t * 4.8828125e-4f;
            }
        }
    }
    // epilogue: s = cnorm[col] - 2*dot; argmin over this wave's 64 cols
    float cn[4];
    #pragma unroll
    for (int nf = 0; nf < 4; ++nf) cn[nf] = cnorm[nb + wn * 64 + nf * 16 + l15];
    int slice = blockIdx.x * 2 + wn;          // 16 ascending 64-bin slices
    #pragma unroll
    for (int mf = 0; mf < 4; ++mf) {
        #pragma unroll
        for (int r = 0; r < 4; ++r) {
            float v = 3.4e38f; int ix = 0;
            #pragma unroll
            for (int nf = 0; nf < 4; ++nf) {  // cols ascend: ties -> lowest
                float sc = cn[nf] - 2.f * acc[mf][nf][r];
                int col = nb + wn * 64 + nf * 16 + l15;
                if (sc < v) { v = sc; ix = col; }
            }
            #pragma unroll
            for (int off = 8; off > 0; off >>= 1) {
                float ov = __shfl_xor(v, off);
                int   oi = __shfl_xor(ix, off);
                if (ov < v || (ov == v && oi < ix)) { v = ov; ix = oi; }
            }
            if (l15 == 0) {
                int row = mb + wm * 64 + mf * 16 + lk * 4 + r;
                pval[row * 16 + slice] = v;
                pidx[row * 16 + slice] = ix;
            }
        }
    }
}

// ---------------------------------------------------------------------------
// Final reduce over 16 ascending bin-slices (strict < keeps lowest index).
// ---------------------------------------------------------------------------
__global__ __launch_bounds__(256) void argmin_final_kernel(
    const float* __restrict__ pval, const int* __restrict__ pidx,
    int* __restrict__ out)
{
    int r = blockIdx.x * 256 + threadIdx.x;
    float best = 3.4e38f; int bi = 0;
    #pragma unroll
    for (int s = 0; s < 16; ++s) {
        float v = pval[r * 16 + s];
        if (v < best) { best = v; bi = pidx[r * 16 + s]; }
    }
    out[r] = bi;
}

extern "C" void kernel_launch(void* const* d_in, const int* in_sizes, int n_in,
                              void* d_out, int out_size, void* d_ws, size_t ws_size,
                              hipStream_t stream) {
    const float* ssl = (const float*)d_in[0];  // [8, 768, 16384]
    const float* W   = (const float*)d_in[1];  // [768][1536], k = 2i+s
    const float* bia = (const float*)d_in[2];  // [768]
    const float* cb  = (const float*)d_in[3];  // [1024, 768]
    int* out = (int*)d_out;                    // [8192] int32 codes

    char* p = (char*)d_ws;
    float* cnorm = (float*)p;  p += 4096;
    f16* Whi  = (f16*)p;  p += (size_t)D * K1 * 2;      // fragment-major planes
    f16* Wlo  = (f16*)p;  p += (size_t)D * K1 * 2;
    f16* CBhi = (f16*)p;  p += (size_t)BINS * D * 2;
    f16* CBlo = (f16*)p;  p += (size_t)BINS * D * 2;
    f16* Ahi  = (f16*)p;  p += (size_t)TQ * K1 * 2;
    f16* Alo  = (f16*)p;  p += (size_t)TQ * K1 * 2;
    f16* Xhi  = (f16*)p;  p += (size_t)TQ * D * 2;
    f16* Xlo  = (f16*)p;  p += (size_t)TQ * D * 2;
    float* pval = (float*)p;  p += (size_t)TQ * 16 * 4;
    int*   pidx = (int*)p;    p += (size_t)TQ * 16 * 4;
    // total ~84.5 MB

    cnorm_kernel<<<BINS, 64, 0, stream>>>(cb, cnorm);
    pack_b_kernel<<<(48 * 48) / 4, 256, 0, stream>>>(W, Whi, Wlo, K1, 48 * 48);
    pack_b_kernel<<<(64 * 24) / 4, 256, 0, stream>>>(cb, CBhi, CBlo, D, 64 * 24);
    pack_a_kernel<<<dim3(NKA, TQ / 128), 256, 0, stream>>>(ssl, Ahi, Alo);
    conv_mfma_kernel<<<dim3(D / 128, TQ / 128), 256, 0, stream>>>(
        Ahi, Alo, Whi, Wlo, bia, Xhi, Xlo);
    score_mfma_kernel<<<dim3(BINS / 128, TQ / 128), 256, 0, stream>>>(
        Xhi, Xlo, CBhi, CBlo, cnorm, pval, pidx);
    argmin_final_kernel<<<TQ / 256, 256, 0, stream>>>(pval, pidx, out);
}

// Round 3
// 562.007 us; speedup vs baseline: 1.4973x; 1.0457x over previous
//
#include <hip/hip_runtime.h>

#define D    768
#define T    16384
#define TQ   8192
#define BINS 1024
#define K1   1536            // conv GEMM K = D*2
#define NKA  (K1 / 32)       // 48 k-blocks (conv operands)
#define NKS  (D / 32)        // 24 k-blocks (score operands)
#define FRAG 1024            // bytes per fragment: 64 lanes x 16 B

typedef _Float16 f16;
typedef _Float16 h8 __attribute__((ext_vector_type(8)));
typedef float    f32x4 __attribute__((ext_vector_type(4)));

// Fragment-major layout, all f16 planes:
//   plane[(r16 * NK + kblk) * 64 + lane] is an h8 (16 B);
//   lane l holds row r16*16 + (l&15), k = kblk*32 + 8*(l>>4) + 0..7
// Matches mfma_f32_16x16x32_f16 A/B operand layout (harness-verified r1/r2).

__device__ __forceinline__ void gl_lds16(const void* g, void* l) {
    __builtin_amdgcn_global_load_lds(
        (const __attribute__((address_space(1))) void*)g,
        (__attribute__((address_space(3))) void*)l, 16, 0, 0);
}

// ---------------------------------------------------------------------------
// cnorm[k] = ||codebook[k]||^2
// ---------------------------------------------------------------------------
__global__ __launch_bounds__(64) void cnorm_kernel(const float* __restrict__ cb,
                                                   float* __restrict__ cnorm) {
    int bin  = blockIdx.x;
    int lane = threadIdx.x;
    const float* row = cb + bin * D;
    float s = 0.f;
    for (int k = lane; k < D; k += 64) { float v = row[k]; s += v * v; }
    #pragma unroll
    for (int off = 32; off > 0; off >>= 1) s += __shfl_down(s, off);
    if (lane == 0) cnorm[bin] = s;
}

// ---------------------------------------------------------------------------
// Row-major fp32 [R][K] -> fragment-major fp16 hi/lo planes. One frag/wave.
// ---------------------------------------------------------------------------
__global__ __launch_bounds__(256) void pack_b_kernel(
    const float* __restrict__ src, f16* __restrict__ hi, f16* __restrict__ lo,
    int K, int nfrag) {
    int wid = threadIdx.x >> 6, lane = threadIdx.x & 63;
    int fid = blockIdx.x * 4 + wid;
    if (fid >= nfrag) return;
    int nk = K >> 5;
    int r16 = fid / nk, kblk = fid - r16 * nk;
    int row = r16 * 16 + (lane & 15);
    int k0  = kblk * 32 + 8 * (lane >> 4);
    const float* s = src + (size_t)row * K + k0;
    float4 v0 = *(const float4*)s;
    float4 v1 = *(const float4*)(s + 4);
    float vv[8] = {v0.x, v0.y, v0.z, v0.w, v1.x, v1.y, v1.z, v1.w};
    h8 vh, vl;
    #pragma unroll
    for (int j = 0; j < 8; ++j) {
        f16 h = (f16)vv[j];
        vh[j] = h;
        vl[j] = (f16)((vv[j] - (float)h) * 2048.f);
    }
    size_t off = ((size_t)fid * 64 + lane) * 8;
    *(h8*)&hi[off] = vh;
    *(h8*)&lo[off] = vl;
}

// ---------------------------------------------------------------------------
// ssl batch-0 [D][T] -> A fragment-major hi/lo, k = 2*i + s (conv k=2,s=2).
// ---------------------------------------------------------------------------
__global__ __launch_bounds__(256) void pack_a_kernel(const float* __restrict__ ssl,
                                                     f16* __restrict__ hi,
                                                     f16* __restrict__ lo) {
    int wid = threadIdx.x >> 6, lane = threadIdx.x & 63;
    int kblk = blockIdx.x;                 // 0..47
    int l15 = lane & 15, lk = lane >> 4;
    #pragma unroll
    for (int q = 0; q < 2; ++q) {
        int tblk = blockIdx.y * 8 + wid * 2 + q;   // t'-group
        int tp = tblk * 16 + l15;
        int i0 = kblk * 16 + 4 * lk;               // input channel base
        float vv[8];
        #pragma unroll
        for (int ii = 0; ii < 4; ++ii) {           // k = 8*lk + 2*ii + s
            float2 v = *(const float2*)&ssl[(size_t)(i0 + ii) * T + 2 * tp];
            vv[2 * ii]     = v.x;
            vv[2 * ii + 1] = v.y;
        }
        h8 vh, vl;
        #pragma unroll
        for (int j = 0; j < 8; ++j) {
            f16 h = (f16)vv[j];
            vh[j] = h;
            vl[j] = (f16)((vv[j] - (float)h) * 2048.f);
        }
        size_t off = ((size_t)(tblk * NKA + kblk) * 64 + lane) * 8;
        *(h8*)&hi[off] = vh;
        *(h8*)&lo[off] = vl;
    }
}

// ---------------------------------------------------------------------------
// Conv as split-fp16 MFMA GEMM. 2-phase double-buffered staging: issue next
// K-tile's global_load_lds BEFORE current tile's ds_read+MFMA, ONE barrier
// per K-step (its vmcnt drain is covered by the MFMA work). Cross terms go
// to a persistent acc2, folded once at the epilogue (no per-step VALU fold).
// Epilogue: 4-slab LDS transpose -> X written fragment-major for score.
// ---------------------------------------------------------------------------
__global__ __launch_bounds__(256, 2) void conv_mfma_kernel(
    const f16* __restrict__ Ah, const f16* __restrict__ Al,   // [TQ/16][NKA] frags
    const f16* __restrict__ Bh, const f16* __restrict__ Bl,   // [D/16][NKA] frags
    const float* __restrict__ bias,
    f16* __restrict__ Xhi, f16* __restrict__ Xlo)             // [TQ/16][NKS] frags
{
    __shared__ __align__(16) char smem[65536];   // 2 x 32 KB buffers
    int tid = threadIdx.x, lane = tid & 63, wid = tid >> 6;
    int wm = wid >> 1, wn = wid & 1;
    int l15 = lane & 15, lk = lane >> 4;
    int mb = blockIdx.y * 128, nb = blockIdx.x * 128;
    int mb16 = mb >> 4, nb16 = nb >> 4;

    // each wave stages one plane (8 frags = 8 KB) per K-step
    const f16* gsrc; int blk16;
    if      (wid == 0) { gsrc = Ah; blk16 = mb16; }
    else if (wid == 1) { gsrc = Al; blk16 = mb16; }
    else if (wid == 2) { gsrc = Bh; blk16 = nb16; }
    else               { gsrc = Bl; blk16 = nb16; }
    const char* gw = (const char*)gsrc + (size_t)blk16 * NKA * FRAG + lane * 16;
    char* lw0 = smem + wid * 8192;
    char* lw1 = smem + 32768 + wid * 8192;

    const f32x4 zero4 = {0.f, 0.f, 0.f, 0.f};
    f32x4 acc[4][4], acc2[4][4];
    #pragma unroll
    for (int i = 0; i < 4; ++i)
        #pragma unroll
        for (int j = 0; j < 4; ++j) { acc[i][j] = zero4; acc2[i][j] = zero4; }

    // prologue: stage kblk=0 into buf0
    #pragma unroll
    for (int f = 0; f < 8; ++f)
        gl_lds16(gw + (size_t)(f * NKA) * FRAG, lw0 + f * FRAG);
    __syncthreads();

    int cur = 0;
    for (int kblk = 0; kblk < NKA; ++kblk) {
        // prefetch next K-tile into the other buffer
        if (kblk + 1 < NKA) {
            char* lwn = cur ? lw0 : lw1;
            #pragma unroll
            for (int f = 0; f < 8; ++f)
                gl_lds16(gw + (size_t)(f * NKA + kblk + 1) * FRAG, lwn + f * FRAG);
        }
        const char* base = smem + cur * 32768;
        h8 ah[4], al[4];
        #pragma unroll
        for (int mf = 0; mf < 4; ++mf) {
            int fo = (wm * 4 + mf) * FRAG + lane * 16;
            ah[mf] = *(const h8*)(base + fo);
            al[mf] = *(const h8*)(base + 8192 + fo);
        }
        #pragma unroll
        for (int nf = 0; nf < 4; ++nf) {
            int fo = (wn * 4 + nf) * FRAG + lane * 16;
            h8 bh = *(const h8*)(base + 16384 + fo);
            h8 bl = *(const h8*)(base + 24576 + fo);
            #pragma unroll
            for (int mf = 0; mf < 4; ++mf) {
                acc [mf][nf] = __builtin_amdgcn_mfma_f32_16x16x32_f16(ah[mf], bh, acc [mf][nf], 0, 0, 0);
                acc2[mf][nf] = __builtin_amdgcn_mfma_f32_16x16x32_f16(ah[mf], bl, acc2[mf][nf], 0, 0, 0);
                acc2[mf][nf] = __builtin_amdgcn_mfma_f32_16x16x32_f16(al[mf], bh, acc2[mf][nf], 0, 0, 0);
            }
        }
        __syncthreads();     // drains this step's prefetch; frees buf[cur]
        cur ^= 1;
    }

    // epilogue: x = acc + acc2/2048 + bias; transpose through LDS to
    // score-fragment layout in 4 slabs of 32 rows (32x132 f32, reuses smem).
    float* sb = (float*)smem;
    float bv[4];
    #pragma unroll
    for (int nf = 0; nf < 4; ++nf) bv[nf] = bias[nb + wn * 64 + nf * 16 + l15];
    #pragma unroll
    for (int s = 0; s < 4; ++s) {
        __syncthreads();
        if (wm == (s >> 1)) {
            #pragma unroll
            for (int mh = 0; mh < 2; ++mh) {
                int mf = (s & 1) * 2 + mh;
                int srow = mh * 16 + lk * 4;
                #pragma unroll
                for (int nf = 0; nf < 4; ++nf) {
                    int scol = wn * 64 + nf * 16 + l15;
                    #pragma unroll
                    for (int r = 0; r < 4; ++r)
                        sb[(srow + r) * 132 + scol] =
                            acc[mf][nf][r] + acc2[mf][nf][r] * 4.8828125e-4f + bv[nf];
                }
            }
        }
        __syncthreads();
        #pragma unroll
        for (int h = 0; h < 2; ++h) {
            int f = wid * 2 + h;          // 0..7: tl = f&1, dbl = f>>1
            int tl = f & 1, dbl = f >> 1;
            int srow = tl * 16 + l15;
            int sd   = dbl * 32 + 8 * lk;
            float vv[8];
            #pragma unroll
            for (int j = 0; j < 8; ++j) vv[j] = sb[srow * 132 + sd + j];
            h8 vh, vl;
            #pragma unroll
            for (int j = 0; j < 8; ++j) {
                f16 hh = (f16)vv[j];
                vh[j] = hh;
                vl[j] = (f16)((vv[j] - (float)hh) * 2048.f);
            }
            int tblk_g = mb16 + s * 2 + tl;
            int dblk_g = (nb >> 5) + dbl;
            size_t off = ((size_t)(tblk_g * NKS + dblk_g) * 64 + lane) * 8;
            *(h8*)&Xhi[off] = vh;
            *(h8*)&Xlo[off] = vl;
        }
    }
}

// ---------------------------------------------------------------------------
// Score: dot via split-fp16 MFMA, same 2-phase dbuf staging (K=768), fused
// s = cnorm - 2*dot + per-row partial argmin (16 slices of 64 bins).
// ---------------------------------------------------------------------------
__global__ __launch_bounds__(256, 2) void score_mfma_kernel(
    const f16* __restrict__ Ah, const f16* __restrict__ Al,   // X frags [TQ/16][NKS]
    const f16* __restrict__ Bh, const f16* __restrict__ Bl,   // CB frags [BINS/16][NKS]
    const float* __restrict__ cnorm,
    float* __restrict__ pval, int* __restrict__ pidx)         // [TQ][16]
{
    __shared__ __align__(16) char smem[65536];
    int tid = threadIdx.x, lane = tid & 63, wid = tid >> 6;
    int wm = wid >> 1, wn = wid & 1;
    int l15 = lane & 15, lk = lane >> 4;
    int mb = blockIdx.y * 128, nb = blockIdx.x * 128;
    int mb16 = mb >> 4, nb16 = nb >> 4;

    const f16* gsrc; int blk16;
    if      (wid == 0) { gsrc = Ah; blk16 = mb16; }
    else if (wid == 1) { gsrc = Al; blk16 = mb16; }
    else if (wid == 2) { gsrc = Bh; blk16 = nb16; }
    else               { gsrc = Bl; blk16 = nb16; }
    const char* gw = (const char*)gsrc + (size_t)blk16 * NKS * FRAG + lane * 16;
    char* lw0 = smem + wid * 8192;
    char* lw1 = smem + 32768 + wid * 8192;

    const f32x4 zero4 = {0.f, 0.f, 0.f, 0.f};
    f32x4 acc[4][4], acc2[4][4];
    #pragma unroll
    for (int i = 0; i < 4; ++i)
        #pragma unroll
        for (int j = 0; j < 4; ++j) { acc[i][j] = zero4; acc2[i][j] = zero4; }

    #pragma unroll
    for (int f = 0; f < 8; ++f)
        gl_lds16(gw + (size_t)(f * NKS) * FRAG, lw0 + f * FRAG);
    __syncthreads();

    int cur = 0;
    for (int kblk = 0; kblk < NKS; ++kblk) {
        if (kblk + 1 < NKS) {
            char* lwn = cur ? lw0 : lw1;
            #pragma unroll
            for (int f = 0; f < 8; ++f)
                gl_lds16(gw + (size_t)(f * NKS + kblk + 1) * FRAG, lwn + f * FRAG);
        }
        const char* base = smem + cur * 32768;
        h8 ah[4], al[4];
        #pragma unroll
        for (int mf = 0; mf < 4; ++mf) {
            int fo = (wm * 4 + mf) * FRAG + lane * 16;
            ah[mf] = *(const h8*)(base + fo);
            al[mf] = *(const h8*)(base + 8192 + fo);
        }
        #pragma unroll
        for (int nf = 0; nf < 4; ++nf) {
            int fo = (wn * 4 + nf) * FRAG + lane * 16;
            h8 bh = *(const h8*)(base + 16384 + fo);
            h8 bl = *(const h8*)(base + 24576 + fo);
            #pragma unroll
            for (int mf = 0; mf < 4; ++mf) {
                acc [mf][nf] = __builtin_amdgcn_mfma_f32_16x16x32_f16(ah[mf], bh, acc [mf][nf], 0, 0, 0);
                acc2[mf][nf] = __builtin_amdgcn_mfma_f32_16x16x32_f16(ah[mf], bl, acc2[mf][nf], 0, 0, 0);
                acc2[mf][nf] = __builtin_amdgcn_mfma_f32_16x16x32_f16(al[mf], bh, acc2[mf][nf], 0, 0, 0);
            }
        }
        __syncthreads();
        cur ^= 1;
    }
    // epilogue: s = cnorm[col] - 2*(acc + acc2/2048); argmin over 64 cols
    float cn[4];
    #pragma unroll
    for (int nf = 0; nf < 4; ++nf) cn[nf] = cnorm[nb + wn * 64 + nf * 16 + l15];
    int slice = blockIdx.x * 2 + wn;          // 16 ascending 64-bin slices
    #pragma unroll
    for (int mf = 0; mf < 4; ++mf) {
        #pragma unroll
        for (int r = 0; r < 4; ++r) {
            float v = 3.4e38f; int ix = 0;
            #pragma unroll
            for (int nf = 0; nf < 4; ++nf) {  // cols ascend: ties -> lowest
                float dot = acc[mf][nf][r] + acc2[mf][nf][r] * 4.8828125e-4f;
                float sc = cn[nf] - 2.f * dot;
                int col = nb + wn * 64 + nf * 16 + l15;
                if (sc < v) { v = sc; ix = col; }
            }
            #pragma unroll
            for (int off = 8; off > 0; off >>= 1) {
                float ov = __shfl_xor(v, off);
                int   oi = __shfl_xor(ix, off);
                if (ov < v || (ov == v && oi < ix)) { v = ov; ix = oi; }
            }
            if (l15 == 0) {
                int row = mb + wm * 64 + mf * 16 + lk * 4 + r;
                pval[row * 16 + slice] = v;
                pidx[row * 16 + slice] = ix;
            }
        }
    }
}

// ---------------------------------------------------------------------------
// Final reduce over 16 ascending bin-slices (strict < keeps lowest index).
// ---------------------------------------------------------------------------
__global__ __launch_bounds__(256) void argmin_final_kernel(
    const float* __restrict__ pval, const int* __restrict__ pidx,
    int* __restrict__ out)
{
    int r = blockIdx.x * 256 + threadIdx.x;
    float best = 3.4e38f; int bi = 0;
    #pragma unroll
    for (int s = 0; s < 16; ++s) {
        float v = pval[r * 16 + s];
        if (v < best) { best = v; bi = pidx[r * 16 + s]; }
    }
    out[r] = bi;
}

extern "C" void kernel_launch(void* const* d_in, const int* in_sizes, int n_in,
                              void* d_out, int out_size, void* d_ws, size_t ws_size,
                              hipStream_t stream) {
    const float* ssl = (const float*)d_in[0];  // [8, 768, 16384]
    const float* W   = (const float*)d_in[1];  // [768][1536], k = 2i+s
    const float* bia = (const float*)d_in[2];  // [768]
    const float* cb  = (const float*)d_in[3];  // [1024, 768]
    int* out = (int*)d_out;                    // [8192] int32 codes

    char* p = (char*)d_ws;
    float* cnorm = (float*)p;  p += 4096;
    f16* Whi  = (f16*)p;  p += (size_t)D * K1 * 2;      // fragment-major planes
    f16* Wlo  = (f16*)p;  p += (size_t)D * K1 * 2;
    f16* CBhi = (f16*)p;  p += (size_t)BINS * D * 2;
    f16* CBlo = (f16*)p;  p += (size_t)BINS * D * 2;
    f16* Ahi  = (f16*)p;  p += (size_t)TQ * K1 * 2;
    f16* Alo  = (f16*)p;  p += (size_t)TQ * K1 * 2;
    f16* Xhi  = (f16*)p;  p += (size_t)TQ * D * 2;
    f16* Xlo  = (f16*)p;  p += (size_t)TQ * D * 2;
    float* pval = (float*)p;  p += (size_t)TQ * 16 * 4;
    int*   pidx = (int*)p;    p += (size_t)TQ * 16 * 4;
    // total ~84.5 MB

    cnorm_kernel<<<BINS, 64, 0, stream>>>(cb, cnorm);
    pack_b_kernel<<<(48 * 48) / 4, 256, 0, stream>>>(W, Whi, Wlo, K1, 48 * 48);
    pack_b_kernel<<<(64 * 24) / 4, 256, 0, stream>>>(cb, CBhi, CBlo, D, 64 * 24);
    pack_a_kernel<<<dim3(NKA, TQ / 128), 256, 0, stream>>>(ssl, Ahi, Alo);
    conv_mfma_kernel<<<dim3(D / 128, TQ / 128), 256, 0, stream>>>(
        Ahi, Alo, Whi, Wlo, bia, Xhi, Xlo);
    score_mfma_kernel<<<dim3(BINS / 128, TQ / 128), 256, 0, stream>>>(
        Xhi, Xlo, CBhi, CBlo, cnorm, pval, pidx);
    argmin_final_kernel<<<TQ / 256, 256, 0, stream>>>(pval, pidx, out);
}

// Round 4
// 553.216 us; speedup vs baseline: 1.5211x; 1.0159x over previous
//
#include <hip/hip_runtime.h>

#define D    768
#define T    16384
#define TQ   8192
#define BINS 1024
#define K1   1536            // conv GEMM K = D*2
#define NKA  (K1 / 32)       // 48 k-blocks (conv operands)
#define NKS  (D / 32)        // 24 k-blocks (score operands)
#define FRAG 1024            // bytes per fragment: 64 lanes x 16 B

#define NFRAG_W  ((D / 16) * NKA)     // 2304 W fragments
#define NFRAG_CB ((BINS / 16) * NKS)  // 1536 codebook fragments
#define NB_PACKB ((NFRAG_W + NFRAG_CB) / 4)   // 960 blocks
#define NB_PACKA (NKA * (TQ / 128))           // 3072 blocks
#define NB_CNORM (BINS / 4)                   // 256 blocks

typedef _Float16 f16;
typedef _Float16 h8 __attribute__((ext_vector_type(8)));
typedef float    f32x4 __attribute__((ext_vector_type(4)));

// Fragment-major layout, all f16 planes:
//   plane[(r16 * NK + kblk) * 64 + lane] is an h8 (16 B);
//   lane l holds row r16*16 + (l&15), k = kblk*32 + 8*(l>>4) + 0..7
// Matches mfma_f32_16x16x32_f16 A/B operand layout (harness-verified r1-r3).

__device__ __forceinline__ void gl_lds16(const void* g, void* l) {
    __builtin_amdgcn_global_load_lds(
        (const __attribute__((address_space(1))) void*)g,
        (__attribute__((address_space(3))) void*)l, 16, 0, 0);
}

// ---------------------------------------------------------------------------
// Fused prep: [0, NB_PACKB)           pack W + codebook into fragment planes
//             [NB_PACKB, +NB_PACKA)   pack ssl batch-0 -> A fragments
//             [.., +NB_CNORM)         cnorm[bin] = ||codebook[bin]||^2
// ---------------------------------------------------------------------------
__global__ __launch_bounds__(256) void prep_kernel(
    const float* __restrict__ ssl, const float* __restrict__ W,
    const float* __restrict__ cb,
    f16* __restrict__ Whi, f16* __restrict__ Wlo,
    f16* __restrict__ CBhi, f16* __restrict__ CBlo,
    f16* __restrict__ Ahi, f16* __restrict__ Alo,
    float* __restrict__ cnorm)
{
    int b = blockIdx.x;
    int wid = threadIdx.x >> 6, lane = threadIdx.x & 63;

    if (b < NB_PACKB) {
        // ---- pack_b: row-major fp32 [R][K] -> fragment-major hi/lo ----
        int fid = b * 4 + wid;
        const float* src; f16* hi; f16* lo; int K, nk, fidl;
        if (fid < NFRAG_W) { src = W;  hi = Whi;  lo = Wlo;  K = K1; nk = NKA; fidl = fid; }
        else               { src = cb; hi = CBhi; lo = CBlo; K = D;  nk = NKS; fidl = fid - NFRAG_W; }
        int r16 = fidl / nk, kblk = fidl - r16 * nk;
        int row = r16 * 16 + (lane & 15);
        int k0  = kblk * 32 + 8 * (lane >> 4);
        const float* s = src + (size_t)row * K + k0;
        float4 v0 = *(const float4*)s;
        float4 v1 = *(const float4*)(s + 4);
        float vv[8] = {v0.x, v0.y, v0.z, v0.w, v1.x, v1.y, v1.z, v1.w};
        h8 vh, vl;
        #pragma unroll
        for (int j = 0; j < 8; ++j) {
            f16 h = (f16)vv[j];
            vh[j] = h;
            vl[j] = (f16)((vv[j] - (float)h) * 2048.f);
        }
        size_t off = ((size_t)fidl * 64 + lane) * 8;
        *(h8*)&hi[off] = vh;
        *(h8*)&lo[off] = vl;
    } else if (b < NB_PACKB + NB_PACKA) {
        // ---- pack_a: ssl batch-0 [D][T] -> A fragments, k = 2*i + s ----
        int idx = b - NB_PACKB;
        int kblk = idx % NKA, yb = idx / NKA;
        int l15 = lane & 15, lk = lane >> 4;
        #pragma unroll
        for (int q = 0; q < 2; ++q) {
            int tblk = yb * 8 + wid * 2 + q;
            int tp = tblk * 16 + l15;
            int i0 = kblk * 16 + 4 * lk;
            float vv[8];
            #pragma unroll
            for (int ii = 0; ii < 4; ++ii) {
                float2 v = *(const float2*)&ssl[(size_t)(i0 + ii) * T + 2 * tp];
                vv[2 * ii]     = v.x;
                vv[2 * ii + 1] = v.y;
            }
            h8 vh, vl;
            #pragma unroll
            for (int j = 0; j < 8; ++j) {
                f16 h = (f16)vv[j];
                vh[j] = h;
                vl[j] = (f16)((vv[j] - (float)h) * 2048.f);
            }
            size_t off = ((size_t)(tblk * NKA + kblk) * 64 + lane) * 8;
            *(h8*)&Ahi[off] = vh;
            *(h8*)&Alo[off] = vl;
        }
    } else {
        // ---- cnorm: one wave per bin ----
        int bin = (b - NB_PACKB - NB_PACKA) * 4 + wid;
        const float* row = cb + (size_t)bin * D;
        float s = 0.f;
        for (int k = lane; k < D; k += 64) { float v = row[k]; s += v * v; }
        #pragma unroll
        for (int off = 32; off > 0; off >>= 1) s += __shfl_down(s, off);
        if (lane == 0) cnorm[bin] = s;
    }
}

// ---------------------------------------------------------------------------
// Conv as split-fp16 MFMA GEMM. 2-phase dbuf staging (prefetch-before-
// compute, one barrier/K-step), persistent acc2 for cross terms (folded at
// epilogue), XCD-chunked block swizzle (grid 6x64 = 384, %8==0 -> bijective):
// each XCD gets 8 M-panels x all 6 N-blocks -> A/W K-chunks stay L2-hot.
// Epilogue: 4-slab LDS transpose -> X written fragment-major for score.
// ---------------------------------------------------------------------------
__global__ __launch_bounds__(256, 2) void conv_mfma_kernel(
    const f16* __restrict__ Ah, const f16* __restrict__ Al,   // [TQ/16][NKA] frags
    const f16* __restrict__ Bh, const f16* __restrict__ Bl,   // [D/16][NKA] frags
    const float* __restrict__ bias,
    f16* __restrict__ Xhi, f16* __restrict__ Xlo)             // [TQ/16][NKS] frags
{
    __shared__ __align__(16) char smem[65536];   // 2 x 32 KB buffers
    int tid = threadIdx.x, lane = tid & 63, wid = tid >> 6;
    int wm = wid >> 1, wn = wid & 1;
    int l15 = lane & 15, lk = lane >> 4;

    // XCD swizzle: orig round-robins over 8 XCDs -> give each XCD a
    // contiguous 48-tile chunk (8 consecutive by x all 6 bx).
    int orig = blockIdx.y * 6 + blockIdx.x;          // grid (6, 64)
    int swz  = (orig & 7) * 48 + (orig >> 3);
    int bx = swz % 6, by = swz / 6;

    int mb = by * 128, nb = bx * 128;
    int mb16 = mb >> 4, nb16 = nb >> 4;

    const f16* gsrc; int blk16;
    if      (wid == 0) { gsrc = Ah; blk16 = mb16; }
    else if (wid == 1) { gsrc = Al; blk16 = mb16; }
    else if (wid == 2) { gsrc = Bh; blk16 = nb16; }
    else               { gsrc = Bl; blk16 = nb16; }
    const char* gw = (const char*)gsrc + (size_t)blk16 * NKA * FRAG + lane * 16;
    char* lw0 = smem + wid * 8192;
    char* lw1 = smem + 32768 + wid * 8192;

    const f32x4 zero4 = {0.f, 0.f, 0.f, 0.f};
    f32x4 acc[4][4], acc2[4][4];
    #pragma unroll
    for (int i = 0; i < 4; ++i)
        #pragma unroll
        for (int j = 0; j < 4; ++j) { acc[i][j] = zero4; acc2[i][j] = zero4; }

    #pragma unroll
    for (int f = 0; f < 8; ++f)
        gl_lds16(gw + (size_t)(f * NKA) * FRAG, lw0 + f * FRAG);
    __syncthreads();

    int cur = 0;
    for (int kblk = 0; kblk < NKA; ++kblk) {
        if (kblk + 1 < NKA) {
            char* lwn = cur ? lw0 : lw1;
            #pragma unroll
            for (int f = 0; f < 8; ++f)
                gl_lds16(gw + (size_t)(f * NKA + kblk + 1) * FRAG, lwn + f * FRAG);
        }
        const char* base = smem + cur * 32768;
        h8 ah[4], al[4];
        #pragma unroll
        for (int mf = 0; mf < 4; ++mf) {
            int fo = (wm * 4 + mf) * FRAG + lane * 16;
            ah[mf] = *(const h8*)(base + fo);
            al[mf] = *(const h8*)(base + 8192 + fo);
        }
        #pragma unroll
        for (int nf = 0; nf < 4; ++nf) {
            int fo = (wn * 4 + nf) * FRAG + lane * 16;
            h8 bh = *(const h8*)(base + 16384 + fo);
            h8 bl = *(const h8*)(base + 24576 + fo);
            #pragma unroll
            for (int mf = 0; mf < 4; ++mf) {
                acc [mf][nf] = __builtin_amdgcn_mfma_f32_16x16x32_f16(ah[mf], bh, acc [mf][nf], 0, 0, 0);
                acc2[mf][nf] = __builtin_amdgcn_mfma_f32_16x16x32_f16(ah[mf], bl, acc2[mf][nf], 0, 0, 0);
                acc2[mf][nf] = __builtin_amdgcn_mfma_f32_16x16x32_f16(al[mf], bh, acc2[mf][nf], 0, 0, 0);
            }
        }
        __syncthreads();
        cur ^= 1;
    }

    // epilogue: x = acc + acc2/2048 + bias; LDS transpose in 4 slabs of
    // 32 rows (32x132 f32, reuses smem) -> fragment-major X for score.
    float* sb = (float*)smem;
    float bv[4];
    #pragma unroll
    for (int nf = 0; nf < 4; ++nf) bv[nf] = bias[nb + wn * 64 + nf * 16 + l15];
    #pragma unroll
    for (int s = 0; s < 4; ++s) {
        __syncthreads();
        if (wm == (s >> 1)) {
            #pragma unroll
            for (int mh = 0; mh < 2; ++mh) {
                int mf = (s & 1) * 2 + mh;
                int srow = mh * 16 + lk * 4;
                #pragma unroll
                for (int nf = 0; nf < 4; ++nf) {
                    int scol = wn * 64 + nf * 16 + l15;
                    #pragma unroll
                    for (int r = 0; r < 4; ++r)
                        sb[(srow + r) * 132 + scol] =
                            acc[mf][nf][r] + acc2[mf][nf][r] * 4.8828125e-4f + bv[nf];
                }
            }
        }
        __syncthreads();
        #pragma unroll
        for (int h = 0; h < 2; ++h) {
            int f = wid * 2 + h;          // 0..7: tl = f&1, dbl = f>>1
            int tl = f & 1, dbl = f >> 1;
            int srow = tl * 16 + l15;
            int sd   = dbl * 32 + 8 * lk;
            float vv[8];
            #pragma unroll
            for (int j = 0; j < 8; ++j) vv[j] = sb[srow * 132 + sd + j];
            h8 vh, vl;
            #pragma unroll
            for (int j = 0; j < 8; ++j) {
                f16 hh = (f16)vv[j];
                vh[j] = hh;
                vl[j] = (f16)((vv[j] - (float)hh) * 2048.f);
            }
            int tblk_g = mb16 + s * 2 + tl;
            int dblk_g = (nb >> 5) + dbl;
            size_t off = ((size_t)(tblk_g * NKS + dblk_g) * 64 + lane) * 8;
            *(h8*)&Xhi[off] = vh;
            *(h8*)&Xlo[off] = vl;
        }
    }
}

// ---------------------------------------------------------------------------
// Score: dot via split-fp16 MFMA, 2-phase dbuf staging, XCD-chunked swizzle
// (grid 8x64 = 512, %8==0), fused s = cnorm - 2*dot + per-row partial argmin.
// ---------------------------------------------------------------------------
__global__ __launch_bounds__(256, 2) void score_mfma_kernel(
    const f16* __restrict__ Ah, const f16* __restrict__ Al,   // X frags [TQ/16][NKS]
    const f16* __restrict__ Bh, const f16* __restrict__ Bl,   // CB frags [BINS/16][NKS]
    const float* __restrict__ cnorm,
    float* __restrict__ pval, int* __restrict__ pidx)         // [TQ][16]
{
    __shared__ __align__(16) char smem[65536];
    int tid = threadIdx.x, lane = tid & 63, wid = tid >> 6;
    int wm = wid >> 1, wn = wid & 1;
    int l15 = lane & 15, lk = lane >> 4;

    int orig = blockIdx.y * 8 + blockIdx.x;          // grid (8, 64)
    int swz  = (orig & 7) * 64 + (orig >> 3);
    int bx = swz & 7, by = swz >> 3;

    int mb = by * 128, nb = bx * 128;
    int mb16 = mb >> 4, nb16 = nb >> 4;

    const f16* gsrc; int blk16;
    if      (wid == 0) { gsrc = Ah; blk16 = mb16; }
    else if (wid == 1) { gsrc = Al; blk16 = mb16; }
    else if (wid == 2) { gsrc = Bh; blk16 = nb16; }
    else               { gsrc = Bl; blk16 = nb16; }
    const char* gw = (const char*)gsrc + (size_t)blk16 * NKS * FRAG + lane * 16;
    char* lw0 = smem + wid * 8192;
    char* lw1 = smem + 32768 + wid * 8192;

    const f32x4 zero4 = {0.f, 0.f, 0.f, 0.f};
    f32x4 acc[4][4], acc2[4][4];
    #pragma unroll
    for (int i = 0; i < 4; ++i)
        #pragma unroll
        for (int j = 0; j < 4; ++j) { acc[i][j] = zero4; acc2[i][j] = zero4; }

    #pragma unroll
    for (int f = 0; f < 8; ++f)
        gl_lds16(gw + (size_t)(f * NKS) * FRAG, lw0 + f * FRAG);
    __syncthreads();

    int cur = 0;
    for (int kblk = 0; kblk < NKS; ++kblk) {
        if (kblk + 1 < NKS) {
            char* lwn = cur ? lw0 : lw1;
            #pragma unroll
            for (int f = 0; f < 8; ++f)
                gl_lds16(gw + (size_t)(f * NKS + kblk + 1) * FRAG, lwn + f * FRAG);
        }
        const char* base = smem + cur * 32768;
        h8 ah[4], al[4];
        #pragma unroll
        for (int mf = 0; mf < 4; ++mf) {
            int fo = (wm * 4 + mf) * FRAG + lane * 16;
            ah[mf] = *(const h8*)(base + fo);
            al[mf] = *(const h8*)(base + 8192 + fo);
        }
        #pragma unroll
        for (int nf = 0; nf < 4; ++nf) {
            int fo = (wn * 4 + nf) * FRAG + lane * 16;
            h8 bh = *(const h8*)(base + 16384 + fo);
            h8 bl = *(const h8*)(base + 24576 + fo);
            #pragma unroll
            for (int mf = 0; mf < 4; ++mf) {
                acc [mf][nf] = __builtin_amdgcn_mfma_f32_16x16x32_f16(ah[mf], bh, acc [mf][nf], 0, 0, 0);
                acc2[mf][nf] = __builtin_amdgcn_mfma_f32_16x16x32_f16(ah[mf], bl, acc2[mf][nf], 0, 0, 0);
                acc2[mf][nf] = __builtin_amdgcn_mfma_f32_16x16x32_f16(al[mf], bh, acc2[mf][nf], 0, 0, 0);
            }
        }
        __syncthreads();
        cur ^= 1;
    }
    // epilogue: s = cnorm[col] - 2*(acc + acc2/2048); argmin over 64 cols
    float cn[4];
    #pragma unroll
    for (int nf = 0; nf < 4; ++nf) cn[nf] = cnorm[nb + wn * 64 + nf * 16 + l15];
    int slice = bx * 2 + wn;                  // 16 ascending 64-bin slices
    #pragma unroll
    for (int mf = 0; mf < 4; ++mf) {
        #pragma unroll
        for (int r = 0; r < 4; ++r) {
            float v = 3.4e38f; int ix = 0;
            #pragma unroll
            for (int nf = 0; nf < 4; ++nf) {  // cols ascend: ties -> lowest
                float dot = acc[mf][nf][r] + acc2[mf][nf][r] * 4.8828125e-4f;
                float sc = cn[nf] - 2.f * dot;
                int col = nb + wn * 64 + nf * 16 + l15;
                if (sc < v) { v = sc; ix = col; }
            }
            #pragma unroll
            for (int off = 8; off > 0; off >>= 1) {
                float ov = __shfl_xor(v, off);
                int   oi = __shfl_xor(ix, off);
                if (ov < v || (ov == v && oi < ix)) { v = ov; ix = oi; }
            }
            if (l15 == 0) {
                int row = mb + wm * 64 + mf * 16 + lk * 4 + r;
                pval[row * 16 + slice] = v;
                pidx[row * 16 + slice] = ix;
            }
        }
    }
}

// ---------------------------------------------------------------------------
// Final reduce over 16 ascending bin-slices (strict < keeps lowest index).
// ---------------------------------------------------------------------------
__global__ __launch_bounds__(256) void argmin_final_kernel(
    const float* __restrict__ pval, const int* __restrict__ pidx,
    int* __restrict__ out)
{
    int r = blockIdx.x * 256 + threadIdx.x;
    float best = 3.4e38f; int bi = 0;
    #pragma unroll
    for (int s = 0; s < 16; ++s) {
        float v = pval[r * 16 + s];
        if (v < best) { best = v; bi = pidx[r * 16 + s]; }
    }
    out[r] = bi;
}

extern "C" void kernel_launch(void* const* d_in, const int* in_sizes, int n_in,
                              void* d_out, int out_size, void* d_ws, size_t ws_size,
                              hipStream_t stream) {
    const float* ssl = (const float*)d_in[0];  // [8, 768, 16384]
    const float* W   = (const float*)d_in[1];  // [768][1536], k = 2i+s
    const float* bia = (const float*)d_in[2];  // [768]
    const float* cb  = (const float*)d_in[3];  // [1024, 768]
    int* out = (int*)d_out;                    // [8192] int32 codes

    char* p = (char*)d_ws;
    float* cnorm = (float*)p;  p += 4096;
    f16* Whi  = (f16*)p;  p += (size_t)D * K1 * 2;      // fragment-major planes
    f16* Wlo  = (f16*)p;  p += (size_t)D * K1 * 2;
    f16* CBhi = (f16*)p;  p += (size_t)BINS * D * 2;
    f16* CBlo = (f16*)p;  p += (size_t)BINS * D * 2;
    f16* Ahi  = (f16*)p;  p += (size_t)TQ * K1 * 2;
    f16* Alo  = (f16*)p;  p += (size_t)TQ * K1 * 2;
    f16* Xhi  = (f16*)p;  p += (size_t)TQ * D * 2;
    f16* Xlo  = (f16*)p;  p += (size_t)TQ * D * 2;
    float* pval = (float*)p;  p += (size_t)TQ * 16 * 4;
    int*   pidx = (int*)p;    p += (size_t)TQ * 16 * 4;
    // total ~84.5 MB

    prep_kernel<<<NB_PACKB + NB_PACKA + NB_CNORM, 256, 0, stream>>>(
        ssl, W, cb, Whi, Wlo, CBhi, CBlo, Ahi, Alo, cnorm);
    conv_mfma_kernel<<<dim3(D / 128, TQ / 128), 256, 0, stream>>>(
        Ahi, Alo, Whi, Wlo, bia, Xhi, Xlo);
    score_mfma_kernel<<<dim3(BINS / 128, TQ / 128), 256, 0, stream>>>(
        Xhi, Xlo, CBhi, CBlo, cnorm, pval, pidx);
    argmin_final_kernel<<<TQ / 256, 256, 0, stream>>>(pval, pidx, out);
}